// Round 5
// baseline (129.519 us; speedup 1.0000x reference)
//
#include <hip/hip_runtime.h>
#include <hip/hip_bf16.h>

typedef __bf16 bf16x8 __attribute__((ext_vector_type(8)));
typedef float  f32x4  __attribute__((ext_vector_type(4)));
typedef float  f32x16 __attribute__((ext_vector_type(16)));
typedef int    i32x4  __attribute__((ext_vector_type(4)));

#define SEQ 4096
#define CIN 64
#define KBLK 64
#define NT (SEQ / KBLK)
#define LOG2E 1.44269504088896340736f

__device__ __forceinline__ void gll16(const void* g, void* l) {
    __builtin_amdgcn_global_load_lds(
        (const __attribute__((address_space(1))) void*)g,
        (__attribute__((address_space(3))) void*)l, 16, 0, 0);
}

__device__ __forceinline__ unsigned cvtpk(float lo, float hi) {
    unsigned r;
    asm("v_cvt_pk_bf16_f32 %0, %1, %2" : "=v"(r) : "v"(lo), "v"(hi));
    return r;
}

// ---------------------------------------------------------------------------
// Kernel 1: fused conv1x1 + PReLU producing Q,K (as [n][4096][32] bf16) and
// Vt (as [n][64][4096] bf16). Q pre-scaled by log2(e) so attn uses exp2.
// ---------------------------------------------------------------------------
__global__ __launch_bounds__(256, 2) void qkv_gen(
    const float* __restrict__ x,
    const float* __restrict__ w1, const float* __restrict__ b1, const float* __restrict__ a1,
    const float* __restrict__ w2, const float* __restrict__ b2, const float* __restrict__ a2,
    const float* __restrict__ w3, const float* __restrict__ b3, const float* __restrict__ a3,
    __bf16* __restrict__ qws, __bf16* __restrict__ kws, __bf16* __restrict__ vtws)
{
    __shared__ float xs[CIN][64];
    __shared__ float wl[CIN][128];
    __shared__ float bl[128];
    __shared__ float al[4];

    const int t  = threadIdx.x;
    const int n  = blockIdx.x >> 6;
    const int p0 = (blockIdx.x & 63) << 6;

    for (int idx = t; idx < 2048; idx += 256) {
        int j = idx >> 6, c = idx & 63;
        wl[c][j]      = w1[idx];
        wl[c][32 + j] = w2[idx];
    }
    for (int idx = t; idx < 4096; idx += 256) {
        int j = idx >> 6, c = idx & 63;
        wl[c][64 + j] = w3[idx];
    }
    if (t < 32) { bl[t] = b1[t]; bl[32 + t] = b2[t]; }
    if (t >= 128 && t < 192) bl[64 + (t - 128)] = b3[t - 128];
    if (t == 0) { al[0] = a1[0]; al[1] = a2[0]; al[2] = a3[0]; }

    const float* xb = x + ((size_t)n * CIN) * SEQ + p0;
    for (int r = 0; r < 16; ++r) {
        int e = r * 256 + t;
        xs[e >> 6][e & 63] = xb[(size_t)(e >> 6) * SEQ + (e & 63)];
    }
    __syncthreads();

    const int p  = t & 63;
    const int g  = t >> 6;
    const int jb = g << 5;
    const float a = (g == 0) ? al[0] : ((g == 1) ? al[1] : al[2]);

    float acc[32];
    #pragma unroll
    for (int j = 0; j < 32; ++j) acc[j] = bl[jb + j];

    for (int c = 0; c < CIN; ++c) {
        float xv = xs[c][p];
        const f32x4* wr = (const f32x4*)&wl[c][jb];
        #pragma unroll
        for (int j4 = 0; j4 < 8; ++j4) {
            f32x4 wv = wr[j4];
            acc[j4*4+0] = fmaf(wv[0], xv, acc[j4*4+0]);
            acc[j4*4+1] = fmaf(wv[1], xv, acc[j4*4+1]);
            acc[j4*4+2] = fmaf(wv[2], xv, acc[j4*4+2]);
            acc[j4*4+3] = fmaf(wv[3], xv, acc[j4*4+3]);
        }
    }
    #pragma unroll
    for (int j = 0; j < 32; ++j) acc[j] = acc[j] >= 0.f ? acc[j] : a * acc[j];

    const int pg = p0 + p;
    if (g <= 1) {
        const float sc = (g == 0) ? LOG2E : 1.0f;
        __bf16* dst = (g == 0 ? qws : kws) + ((size_t)n * SEQ + pg) * 32;
        #pragma unroll
        for (int v8 = 0; v8 < 4; ++v8) {
            bf16x8 o;
            #pragma unroll
            for (int i = 0; i < 8; ++i) o[i] = (__bf16)(acc[v8*8+i] * sc);
            *(bf16x8*)(dst + v8*8) = o;
        }
    } else {
        __bf16* dst = vtws + ((size_t)n * CIN + (jb - 64)) * SEQ + pg;
        #pragma unroll
        for (int j = 0; j < 32; ++j) dst[(size_t)j * SEQ] = (__bf16)acc[j];
    }
}

// ---------------------------------------------------------------------------
// Kernel 2: flash attention, 32x32 MFMA, in-register P (cvt_pk + permlane32).
// 512 blocks (n=bid&7 XCD-affine, qblk=bid>>3), 2 waves x 32 q-rows.
// KBLK=64, LDS = dbuf(K 4KB + Vt 8KB) = 24 KB -> 6 blocks/CU (3 waves/SIMD).
// S^T = mfma32x32(K,Q) -> lane q=lane&31, 16 keys in regs. Softmax lane-local.
// P redistributed to PV B-frag layout with 8 cvt_pk + 4 permlane32_swap per
// 32-key tile. O^T = mfma32x32(Vt, P^T) -> output layout directly.
// K swz: byte^=((row>>1)&3)<<4; V swz: byte^=(row&7)<<4 (pre-swizzled source).
// ---------------------------------------------------------------------------
__global__ __launch_bounds__(128) void attn(
    const __bf16* __restrict__ qws, const __bf16* __restrict__ kws,
    const __bf16* __restrict__ vtws, const float* __restrict__ x,
    float* __restrict__ out)
{
    __shared__ __align__(16) char ktl[2][KBLK * 64];    // 2 x 4 KB  [key][32d]
    __shared__ __align__(16) char vtl[2][CIN * KBLK*2]; // 2 x 8 KB  [dv][64k]

    const int t    = threadIdx.x;    // 128 threads, 2 waves
    const int lane = t & 63;
    const int wid  = t >> 6;
    const int n    = blockIdx.x & 7;
    const int qblk = blockIdx.x >> 3;
    const int l31  = lane & 31;
    const int h    = lane >> 5;
    const int qbase = qblk * 64 + wid * 32;
    const int ksw  = ((l31 >> 1) & 3) << 4;   // K read swizzle (row = kt*32+l31)
    const int vsw  = (l31 & 7) << 4;          // V read swizzle (row = fd2*32+l31)

    const char* kb = (const char*)(kws + (size_t)n * SEQ * 32);
    const char* vb = (const char*)(vtws + (size_t)n * CIN * SEQ);

    // Q B-frags: lane holds Q[qbase+l31][h*8+i (+16*step)]
    const char* qp = (const char*)(qws + (size_t)n * SEQ * 32)
                     + (size_t)(qbase + l31) * 64 + h * 16;
    const bf16x8 qf0 = *(const bf16x8*)(qp);
    const bf16x8 qf1 = *(const bf16x8*)(qp + 32);

    f32x16 of0 = {}, of1 = {};     // O^T accum, fd2=0/1: q=l31, dv=(r&3)+8*(r>>2)+4h (+32)
    float ls = 0.f;

    auto stage = [&](int k0n, int buf) {
        #pragma unroll
        for (int j = 0; j < 2; ++j) {          // K: 4 KB, rows 64 B
            int L   = j * 2048 + t * 16;
            int row = L >> 6;
            int c16 = (t & 3) ^ ((t >> 3) & 3);
            gll16(kb + (size_t)(k0n + row) * 64 + c16 * 16, &ktl[buf][0] + L);
        }
        #pragma unroll
        for (int j = 0; j < 4; ++j) {          // V: 8 KB, rows 128 B
            int L    = j * 2048 + t * 16;
            int row  = L >> 7;
            int colb = ((t & 7) ^ ((t >> 3) & 7)) << 4;
            gll16(vb + (size_t)row * 8192 + (size_t)k0n * 2 + colb, &vtl[buf][0] + L);
        }
    };

    stage(0, 0);
    __syncthreads();

    for (int tt = 0; tt < NT; ++tt) {
        const int cur = tt & 1;
        if (tt + 1 < NT) stage((tt + 1) * KBLK, cur ^ 1);

        const char* kc_ = &ktl[cur][0];
        const char* vc_ = &vtl[cur][0];

        unsigned c0[8], c1[8];   // P B-frag words, kt=0 (keys 0..31), kt=1 (32..63)

        #pragma unroll
        for (int kti = 0; kti < 2; ++kti) {
            // ---- S^T tile: 32 keys x 32 q, 2 chained MFMAs over d ----
            const char* krow = kc_ + (size_t)(kti * 32 + l31) * 64;
            bf16x8 kf0 = *(const bf16x8*)(krow + ((h * 16) ^ ksw));
            bf16x8 kf1 = *(const bf16x8*)(krow + ((32 + h * 16) ^ ksw));
            f32x16 s = {};
            __builtin_amdgcn_s_setprio(1);
            s = __builtin_amdgcn_mfma_f32_32x32x16_bf16(kf0, qf0, s, 0, 0, 0);
            s = __builtin_amdgcn_mfma_f32_32x32x16_bf16(kf1, qf1, s, 0, 0, 0);
            __builtin_amdgcn_s_setprio(0);

            // ---- softmax: exp2, accumulate l, pack to bf16 pairs ----
            float p[16];
            #pragma unroll
            for (int r = 0; r < 16; ++r) {
                p[r] = __builtin_exp2f(s[r]);
                ls += p[r];
            }
            unsigned* c = kti ? c1 : c0;
            #pragma unroll
            for (int j = 0; j < 4; ++j) {
                c[j]     = cvtpk(p[2*j],     p[2*j + 1]);     // keys lo-block
                c[4 + j] = cvtpk(p[8 + 2*j], p[9 + 2*j]);     // keys hi-block
            }
            // redistribute halves: B reg j holds keys {h*8+2j, h*8+2j+1}
            asm("v_permlane32_swap_b32 %0, %1" : "+v"(c[0]), "+v"(c[2]));
            asm("v_permlane32_swap_b32 %0, %1" : "+v"(c[1]), "+v"(c[3]));
            asm("v_permlane32_swap_b32 %0, %1" : "+v"(c[4]), "+v"(c[6]));
            asm("v_permlane32_swap_b32 %0, %1" : "+v"(c[5]), "+v"(c[7]));
        }

        // ---- O^T += Vt . P^T : 4 key-steps x 2 dv-tiles ----
        __builtin_amdgcn_s_setprio(1);
        #pragma unroll
        for (int s4 = 0; s4 < 4; ++s4) {
            const unsigned* cs = (s4 < 2) ? c0 : c1;
            const int sl = (s4 & 1) * 4;
            i32x4 bi = { (int)cs[sl], (int)cs[sl+1], (int)cs[sl+2], (int)cs[sl+3] };
            bf16x8 pf = __builtin_bit_cast(bf16x8, bi);
            const int colv = (s4 * 32 + h * 16) ^ vsw;
            bf16x8 vf0 = *(const bf16x8*)(vc_ + (size_t)l31 * 128 + colv);
            bf16x8 vf1 = *(const bf16x8*)(vc_ + (size_t)(32 + l31) * 128 + colv);
            of0 = __builtin_amdgcn_mfma_f32_32x32x16_bf16(vf0, pf, of0, 0, 0, 0);
            of1 = __builtin_amdgcn_mfma_f32_32x32x16_bf16(vf1, pf, of1, 0, 0, 0);
        }
        __builtin_amdgcn_s_setprio(0);

        __syncthreads();
    }

    // ---- epilogue: combine halves' l, normalize, residual ----
    float ll = ls + __shfl_xor(ls, 32);
    const float inv = 1.f / ll;
    const int qg = qbase + l31;
    const float* xb = x + (size_t)n * CIN * SEQ;
    float* ob = out + (size_t)n * CIN * SEQ;
    #pragma unroll
    for (int r = 0; r < 16; ++r) {
        int dv = (r & 3) + 8 * (r >> 2) + 4 * h;
        size_t i0 = (size_t)dv * SEQ + qg;
        size_t i1 = (size_t)(dv + 32) * SEQ + qg;
        ob[i0] = of0[r] * inv + xb[i0];
        ob[i1] = of1[r] * inv + xb[i1];
    }
}

extern "C" void kernel_launch(void* const* d_in, const int* in_sizes, int n_in,
                              void* d_out, int out_size, void* d_ws, size_t ws_size,
                              hipStream_t stream)
{
    (void)in_sizes; (void)n_in; (void)out_size; (void)ws_size;
    const float* x  = (const float*)d_in[0];
    const float* w1 = (const float*)d_in[1];
    const float* b1 = (const float*)d_in[2];
    const float* a1 = (const float*)d_in[3];
    const float* w2 = (const float*)d_in[4];
    const float* b2 = (const float*)d_in[5];
    const float* a2 = (const float*)d_in[6];
    const float* w3 = (const float*)d_in[7];
    const float* b3 = (const float*)d_in[8];
    const float* a3 = (const float*)d_in[9];
    float* out = (float*)d_out;

    __bf16* qws  = (__bf16*)d_ws;                       // 2 MB
    __bf16* kws  = qws + (size_t)8 * SEQ * 32;          // 2 MB
    __bf16* vtws = kws + (size_t)8 * SEQ * 32;          // 4 MB

    hipLaunchKernelGGL(qkv_gen, dim3(512), dim3(256), 0, stream,
                       x, w1, b1, a1, w2, b2, a2, w3, b3, a3, qws, kws, vtws);
    hipLaunchKernelGGL(attn, dim3(512), dim3(128), 0, stream,
                       qws, kws, vtws, x, out);
}

// Round 6
// 99.573 us; speedup vs baseline: 1.3007x; 1.3007x over previous
//
#include <hip/hip_runtime.h>
#include <hip/hip_bf16.h>

typedef __bf16 bf16x8 __attribute__((ext_vector_type(8)));
typedef float  f32x4  __attribute__((ext_vector_type(4)));
typedef float  f32x16 __attribute__((ext_vector_type(16)));
typedef int    i32x4  __attribute__((ext_vector_type(4)));

#define SEQ 4096
#define CIN 64
#define KBLK 64
#define KSPLIT 4
#define KCHUNK (SEQ / KSPLIT)          // 1024 keys per block
#define NTC (KCHUNK / KBLK)            // 16 iters
#define LOG2E 1.44269504088896340736f

__device__ __forceinline__ void gll16(const void* g, void* l) {
    __builtin_amdgcn_global_load_lds(
        (const __attribute__((address_space(1))) void*)g,
        (__attribute__((address_space(3))) void*)l, 16, 0, 0);
}

__device__ __forceinline__ unsigned cvtpk(float lo, float hi) {
    unsigned r;
    asm("v_cvt_pk_bf16_f32 %0, %1, %2" : "=v"(r) : "v"(lo), "v"(hi));
    return r;
}

// ---------------------------------------------------------------------------
// Kernel 1: fused conv1x1 + PReLU producing Q,K (as [n][4096][32] bf16) and
// Vt (as [n][64][4096] bf16). Q pre-scaled by log2(e) so attn uses exp2.
// ---------------------------------------------------------------------------
__global__ __launch_bounds__(256, 2) void qkv_gen(
    const float* __restrict__ x,
    const float* __restrict__ w1, const float* __restrict__ b1, const float* __restrict__ a1,
    const float* __restrict__ w2, const float* __restrict__ b2, const float* __restrict__ a2,
    const float* __restrict__ w3, const float* __restrict__ b3, const float* __restrict__ a3,
    __bf16* __restrict__ qws, __bf16* __restrict__ kws, __bf16* __restrict__ vtws)
{
    __shared__ float xs[CIN][64];
    __shared__ float wl[CIN][128];
    __shared__ float bl[128];
    __shared__ float al[4];

    const int t  = threadIdx.x;
    const int n  = blockIdx.x >> 6;
    const int p0 = (blockIdx.x & 63) << 6;

    for (int idx = t; idx < 2048; idx += 256) {
        int j = idx >> 6, c = idx & 63;
        wl[c][j]      = w1[idx];
        wl[c][32 + j] = w2[idx];
    }
    for (int idx = t; idx < 4096; idx += 256) {
        int j = idx >> 6, c = idx & 63;
        wl[c][64 + j] = w3[idx];
    }
    if (t < 32) { bl[t] = b1[t]; bl[32 + t] = b2[t]; }
    if (t >= 128 && t < 192) bl[64 + (t - 128)] = b3[t - 128];
    if (t == 0) { al[0] = a1[0]; al[1] = a2[0]; al[2] = a3[0]; }

    const float* xb = x + ((size_t)n * CIN) * SEQ + p0;
    for (int r = 0; r < 16; ++r) {
        int e = r * 256 + t;
        xs[e >> 6][e & 63] = xb[(size_t)(e >> 6) * SEQ + (e & 63)];
    }
    __syncthreads();

    const int p  = t & 63;
    const int g  = t >> 6;
    const int jb = g << 5;
    const float a = (g == 0) ? al[0] : ((g == 1) ? al[1] : al[2]);

    float acc[32];
    #pragma unroll
    for (int j = 0; j < 32; ++j) acc[j] = bl[jb + j];

    for (int c = 0; c < CIN; ++c) {
        float xv = xs[c][p];
        const f32x4* wr = (const f32x4*)&wl[c][jb];
        #pragma unroll
        for (int j4 = 0; j4 < 8; ++j4) {
            f32x4 wv = wr[j4];
            acc[j4*4+0] = fmaf(wv[0], xv, acc[j4*4+0]);
            acc[j4*4+1] = fmaf(wv[1], xv, acc[j4*4+1]);
            acc[j4*4+2] = fmaf(wv[2], xv, acc[j4*4+2]);
            acc[j4*4+3] = fmaf(wv[3], xv, acc[j4*4+3]);
        }
    }
    #pragma unroll
    for (int j = 0; j < 32; ++j) acc[j] = acc[j] >= 0.f ? acc[j] : a * acc[j];

    const int pg = p0 + p;
    if (g <= 1) {
        const float sc = (g == 0) ? LOG2E : 1.0f;
        __bf16* dst = (g == 0 ? qws : kws) + ((size_t)n * SEQ + pg) * 32;
        #pragma unroll
        for (int v8 = 0; v8 < 4; ++v8) {
            bf16x8 o;
            #pragma unroll
            for (int i = 0; i < 8; ++i) o[i] = (__bf16)(acc[v8*8+i] * sc);
            *(bf16x8*)(dst + v8*8) = o;
        }
    } else {
        __bf16* dst = vtws + ((size_t)n * CIN + (jb - 64)) * SEQ + pg;
        #pragma unroll
        for (int j = 0; j < 32; ++j) dst[(size_t)j * SEQ] = (__bf16)acc[j];
    }
}

// ---------------------------------------------------------------------------
// Kernel 2: flash attention, 32x32 MFMA, in-register P, K-SPLIT partials.
// Fixed-max softmax => partial (O,l) over disjoint key chunks are additive:
// each block handles 1024 keys and atomically accumulates f32 partials.
// Grid 1024: n=bid&7 (XCD-affine), qblk=(bid>>3)&31, ks=bid>>8.
// 4 waves x 32 q (128 q/block). LDS = dbuf(K 4KB + V 8KB) = 24 KB.
// => 4096 waves total (16 waves/CU) vs 1024 before: fixes the occupancy wall.
// K swz: byte^=((row>>1)&3)<<4; V swz: byte^=(row&7)<<4 (pre-swizzled source).
// ---------------------------------------------------------------------------
__global__ __launch_bounds__(256) void attn(
    const __bf16* __restrict__ qws, const __bf16* __restrict__ kws,
    const __bf16* __restrict__ vtws,
    float* __restrict__ Ows, float* __restrict__ lws)
{
    __shared__ __align__(16) char ktl[2][KBLK * 64];     // 2 x 4 KB  [key][32d]
    __shared__ __align__(16) char vtl[2][CIN * KBLK*2];  // 2 x 8 KB  [dv][64k]

    const int t    = threadIdx.x;     // 256 threads, 4 waves
    const int lane = t & 63;
    const int wid  = t >> 6;
    const int n    = blockIdx.x & 7;
    const int qblk = (blockIdx.x >> 3) & 31;
    const int ks   = blockIdx.x >> 8;
    const int l31  = lane & 31;
    const int h    = lane >> 5;
    const int qbase = qblk * 128 + wid * 32;
    const int kbase = ks * KCHUNK;
    const int ksw  = ((l31 >> 1) & 3) << 4;
    const int vsw  = (l31 & 7) << 4;

    const char* kb = (const char*)(kws + (size_t)n * SEQ * 32);
    const char* vb = (const char*)(vtws + (size_t)n * CIN * SEQ);

    const char* qp = (const char*)(qws + (size_t)n * SEQ * 32)
                     + (size_t)(qbase + l31) * 64 + h * 16;
    const bf16x8 qf0 = *(const bf16x8*)(qp);
    const bf16x8 qf1 = *(const bf16x8*)(qp + 32);

    f32x16 of0 = {}, of1 = {};
    float ls = 0.f;

    // stage: 256 threads cover K 4KB in one shot, V 8KB in two.
    auto stage = [&](int k0n, int buf) {
        {
            int row = t >> 2;
            int c16 = (t & 3) ^ ((t >> 3) & 3);
            gll16(kb + (size_t)(k0n + row) * 64 + c16 * 16, &ktl[buf][0] + t * 16);
        }
        #pragma unroll
        for (int j = 0; j < 2; ++j) {
            int L   = j * 4096 + t * 16;
            int row = j * 32 + (t >> 3);
            int c16 = (t & 7) ^ ((t >> 3) & 7);
            gll16(vb + (size_t)row * 8192 + (size_t)k0n * 2 + c16 * 16, &vtl[buf][0] + L);
        }
    };

    stage(kbase, 0);
    __syncthreads();

    for (int tt = 0; tt < NTC; ++tt) {
        const int cur = tt & 1;
        if (tt + 1 < NTC) stage(kbase + (tt + 1) * KBLK, cur ^ 1);

        const char* kc_ = &ktl[cur][0];
        const char* vc_ = &vtl[cur][0];

        unsigned c0[8], c1[8];

        #pragma unroll
        for (int kti = 0; kti < 2; ++kti) {
            const char* krow = kc_ + (size_t)(kti * 32 + l31) * 64;
            bf16x8 kf0 = *(const bf16x8*)(krow + ((h * 16) ^ ksw));
            bf16x8 kf1 = *(const bf16x8*)(krow + ((32 + h * 16) ^ ksw));
            f32x16 s = {};
            __builtin_amdgcn_s_setprio(1);
            s = __builtin_amdgcn_mfma_f32_32x32x16_bf16(kf0, qf0, s, 0, 0, 0);
            s = __builtin_amdgcn_mfma_f32_32x32x16_bf16(kf1, qf1, s, 0, 0, 0);
            __builtin_amdgcn_s_setprio(0);

            float p[16];
            #pragma unroll
            for (int r = 0; r < 16; ++r) {
                p[r] = __builtin_exp2f(s[r]);
                ls += p[r];
            }
            unsigned* c = kti ? c1 : c0;
            #pragma unroll
            for (int j = 0; j < 4; ++j) {
                c[j]     = cvtpk(p[2*j],     p[2*j + 1]);
                c[4 + j] = cvtpk(p[8 + 2*j], p[9 + 2*j]);
            }
            asm("v_permlane32_swap_b32 %0, %1" : "+v"(c[0]), "+v"(c[2]));
            asm("v_permlane32_swap_b32 %0, %1" : "+v"(c[1]), "+v"(c[3]));
            asm("v_permlane32_swap_b32 %0, %1" : "+v"(c[4]), "+v"(c[6]));
            asm("v_permlane32_swap_b32 %0, %1" : "+v"(c[5]), "+v"(c[7]));
        }

        __builtin_amdgcn_s_setprio(1);
        #pragma unroll
        for (int s4 = 0; s4 < 4; ++s4) {
            const unsigned* cs = (s4 < 2) ? c0 : c1;
            const int sl = (s4 & 1) * 4;
            i32x4 bi = { (int)cs[sl], (int)cs[sl+1], (int)cs[sl+2], (int)cs[sl+3] };
            bf16x8 pf = __builtin_bit_cast(bf16x8, bi);
            const int colv = (s4 * 32 + h * 16) ^ vsw;
            bf16x8 vf0 = *(const bf16x8*)(vc_ + (size_t)l31 * 128 + colv);
            bf16x8 vf1 = *(const bf16x8*)(vc_ + (size_t)(32 + l31) * 128 + colv);
            of0 = __builtin_amdgcn_mfma_f32_32x32x16_bf16(vf0, pf, of0, 0, 0, 0);
            of1 = __builtin_amdgcn_mfma_f32_32x32x16_bf16(vf1, pf, of1, 0, 0, 0);
        }
        __builtin_amdgcn_s_setprio(0);

        __syncthreads();
    }

    // ---- epilogue: accumulate partial O and l (f32 atomics) ----
    const int qg = qbase + l31;
    float* Ob = Ows + (size_t)n * CIN * SEQ;
    #pragma unroll
    for (int r = 0; r < 16; ++r) {
        int dv = (r & 3) + 8 * (r >> 2) + 4 * h;
        unsafeAtomicAdd(Ob + (size_t)dv * SEQ + qg,        of0[r]);
        unsafeAtomicAdd(Ob + (size_t)(dv + 32) * SEQ + qg, of1[r]);
    }
    unsafeAtomicAdd(lws + n * SEQ + qg, ls);   // each half-lane adds its key-subset sum
}

// ---------------------------------------------------------------------------
// Kernel 3: out = O/l + x  (vectorized f32x4 grid-stride)
// ---------------------------------------------------------------------------
__global__ __launch_bounds__(256) void combine(
    const float* __restrict__ Ows, const float* __restrict__ lws,
    const float* __restrict__ x, float* __restrict__ out)
{
    const int total = 8 * CIN * SEQ / 4;     // 524288 f32x4
    for (int i = blockIdx.x * 256 + threadIdx.x; i < total; i += gridDim.x * 256) {
        int q4 = i & (SEQ / 4 - 1);
        int nd = i >> 10;                    // n*64 + dv
        int n  = nd >> 6;
        f32x4 o4 = *(const f32x4*)(Ows + (size_t)i * 4);
        f32x4 l4 = *(const f32x4*)(lws + (size_t)n * SEQ + q4 * 4);
        f32x4 x4 = *(const f32x4*)(x + (size_t)i * 4);
        f32x4 r;
        r[0] = o4[0] / l4[0] + x4[0];
        r[1] = o4[1] / l4[1] + x4[1];
        r[2] = o4[2] / l4[2] + x4[2];
        r[3] = o4[3] / l4[3] + x4[3];
        *(f32x4*)(out + (size_t)i * 4) = r;
    }
}

extern "C" void kernel_launch(void* const* d_in, const int* in_sizes, int n_in,
                              void* d_out, int out_size, void* d_ws, size_t ws_size,
                              hipStream_t stream)
{
    (void)in_sizes; (void)n_in; (void)out_size; (void)ws_size;
    const float* x  = (const float*)d_in[0];
    const float* w1 = (const float*)d_in[1];
    const float* b1 = (const float*)d_in[2];
    const float* a1 = (const float*)d_in[3];
    const float* w2 = (const float*)d_in[4];
    const float* b2 = (const float*)d_in[5];
    const float* a2 = (const float*)d_in[6];
    const float* w3 = (const float*)d_in[7];
    const float* b3 = (const float*)d_in[8];
    const float* a3 = (const float*)d_in[9];
    float* out = (float*)d_out;

    char* ws = (char*)d_ws;
    __bf16* qws  = (__bf16*)(ws);                        // 2 MB
    __bf16* kws  = (__bf16*)(ws + (2u << 20));           // 2 MB
    __bf16* vtws = (__bf16*)(ws + (4u << 20));           // 4 MB
    float*  Ows  = (float*)(ws + (8u << 20));            // 8 MB  [8][64][4096] f32
    float*  lws  = (float*)(ws + (16u << 20));           // 128 KB [8][4096] f32

    hipMemsetAsync(Ows, 0, (8u << 20) + (128u << 10), stream);
    hipLaunchKernelGGL(qkv_gen, dim3(512), dim3(256), 0, stream,
                       x, w1, b1, a1, w2, b2, a2, w3, b3, a3, qws, kws, vtws);
    hipLaunchKernelGGL(attn, dim3(8 * 32 * KSPLIT), dim3(256), 0, stream,
                       qws, kws, vtws, Ows, lws);
    hipLaunchKernelGGL(combine, dim3(1024), dim3(256), 0, stream,
                       Ows, lws, x, out);
}

// Round 7
// 90.942 us; speedup vs baseline: 1.4242x; 1.0949x over previous
//
#include <hip/hip_runtime.h>
#include <hip/hip_bf16.h>

typedef __bf16 bf16x8 __attribute__((ext_vector_type(8)));
typedef float  f32x4  __attribute__((ext_vector_type(4)));
typedef float  f32x16 __attribute__((ext_vector_type(16)));
typedef int    i32x4  __attribute__((ext_vector_type(4)));

#define SEQ 4096
#define CIN 64
#define KBLK 64
#define KSPLIT 4
#define KCHUNK (SEQ / KSPLIT)          // 1024 keys per block
#define NTC (KCHUNK / KBLK)            // 16 iters
#define LOG2E 1.44269504088896340736f

__device__ __forceinline__ void gll16(const void* g, void* l) {
    __builtin_amdgcn_global_load_lds(
        (const __attribute__((address_space(1))) void*)g,
        (__attribute__((address_space(3))) void*)l, 16, 0, 0);
}

__device__ __forceinline__ unsigned cvtpk(float lo, float hi) {
    unsigned r;
    asm("v_cvt_pk_bf16_f32 %0, %1, %2" : "=v"(r) : "v"(lo), "v"(hi));
    return r;
}

// ---------------------------------------------------------------------------
// Kernel 1: fused conv1x1 + PReLU producing Q,K (as [n][4096][32] bf16) and
// Vt (as [n][64][4096] bf16). Q pre-scaled by log2(e) so attn uses exp2.
// ---------------------------------------------------------------------------
__global__ __launch_bounds__(256, 2) void qkv_gen(
    const float* __restrict__ x,
    const float* __restrict__ w1, const float* __restrict__ b1, const float* __restrict__ a1,
    const float* __restrict__ w2, const float* __restrict__ b2, const float* __restrict__ a2,
    const float* __restrict__ w3, const float* __restrict__ b3, const float* __restrict__ a3,
    __bf16* __restrict__ qws, __bf16* __restrict__ kws, __bf16* __restrict__ vtws)
{
    __shared__ float xs[CIN][64];
    __shared__ float wl[CIN][128];
    __shared__ float bl[128];
    __shared__ float al[4];

    const int t  = threadIdx.x;
    const int n  = blockIdx.x >> 6;
    const int p0 = (blockIdx.x & 63) << 6;

    for (int idx = t; idx < 2048; idx += 256) {
        int j = idx >> 6, c = idx & 63;
        wl[c][j]      = w1[idx];
        wl[c][32 + j] = w2[idx];
    }
    for (int idx = t; idx < 4096; idx += 256) {
        int j = idx >> 6, c = idx & 63;
        wl[c][64 + j] = w3[idx];
    }
    if (t < 32) { bl[t] = b1[t]; bl[32 + t] = b2[t]; }
    if (t >= 128 && t < 192) bl[64 + (t - 128)] = b3[t - 128];
    if (t == 0) { al[0] = a1[0]; al[1] = a2[0]; al[2] = a3[0]; }

    const float* xb = x + ((size_t)n * CIN) * SEQ + p0;
    for (int r = 0; r < 16; ++r) {
        int e = r * 256 + t;
        xs[e >> 6][e & 63] = xb[(size_t)(e >> 6) * SEQ + (e & 63)];
    }
    __syncthreads();

    const int p  = t & 63;
    const int g  = t >> 6;
    const int jb = g << 5;
    const float a = (g == 0) ? al[0] : ((g == 1) ? al[1] : al[2]);

    float acc[32];
    #pragma unroll
    for (int j = 0; j < 32; ++j) acc[j] = bl[jb + j];

    for (int c = 0; c < CIN; ++c) {
        float xv = xs[c][p];
        const f32x4* wr = (const f32x4*)&wl[c][jb];
        #pragma unroll
        for (int j4 = 0; j4 < 8; ++j4) {
            f32x4 wv = wr[j4];
            acc[j4*4+0] = fmaf(wv[0], xv, acc[j4*4+0]);
            acc[j4*4+1] = fmaf(wv[1], xv, acc[j4*4+1]);
            acc[j4*4+2] = fmaf(wv[2], xv, acc[j4*4+2]);
            acc[j4*4+3] = fmaf(wv[3], xv, acc[j4*4+3]);
        }
    }
    #pragma unroll
    for (int j = 0; j < 32; ++j) acc[j] = acc[j] >= 0.f ? acc[j] : a * acc[j];

    const int pg = p0 + p;
    if (g <= 1) {
        const float sc = (g == 0) ? LOG2E : 1.0f;
        __bf16* dst = (g == 0 ? qws : kws) + ((size_t)n * SEQ + pg) * 32;
        #pragma unroll
        for (int v8 = 0; v8 < 4; ++v8) {
            bf16x8 o;
            #pragma unroll
            for (int i = 0; i < 8; ++i) o[i] = (__bf16)(acc[v8*8+i] * sc);
            *(bf16x8*)(dst + v8*8) = o;
        }
    } else {
        __bf16* dst = vtws + ((size_t)n * CIN + (jb - 64)) * SEQ + pg;
        #pragma unroll
        for (int j = 0; j < 32; ++j) dst[(size_t)j * SEQ] = (__bf16)acc[j];
    }
}

// ---------------------------------------------------------------------------
// Kernel 2: flash attention, 32x32 MFMA, in-register P, K-SPLIT partials,
// 3-deep staging pipeline with COUNTED vmcnt (never drained to 0 in-loop)
// and raw s_barrier (no compiler vmcnt(0) drain).
// Per iter: s_waitcnt vmcnt(3) [tile t's 3 stage-instrs done; t+1 in flight]
//           -> s_barrier -> issue stage(t+2) -> compute(t).
// Grid 1024: n=bid&7 (XCD-affine), qblk=(bid>>3)&31, ks=bid>>8.
// 4 waves x 32 q. LDS = 3 x (K 4KB + V 8KB) = 36 KB -> 4 blocks/CU.
// K swz: byte^=((row>>1)&3)<<4; V swz: byte^=(row&7)<<4 (pre-swizzled source).
// ---------------------------------------------------------------------------
__global__ __launch_bounds__(256, 4) void attn(
    const __bf16* __restrict__ qws, const __bf16* __restrict__ kws,
    const __bf16* __restrict__ vtws,
    float* __restrict__ Ows, float* __restrict__ lws)
{
    __shared__ __align__(16) char stg[3][12288];   // per stage: K @0 (4KB), V @4096 (8KB)

    const int t    = threadIdx.x;     // 256 threads, 4 waves
    const int lane = t & 63;
    const int n    = blockIdx.x & 7;
    const int qblk = (blockIdx.x >> 3) & 31;
    const int ks   = blockIdx.x >> 8;
    const int wid  = t >> 6;
    const int l31  = lane & 31;
    const int h    = lane >> 5;
    const int qbase = qblk * 128 + wid * 32;
    const int kbase = ks * KCHUNK;
    const int ksw  = ((l31 >> 1) & 3) << 4;
    const int vsw  = (l31 & 7) << 4;

    const char* kb = (const char*)(kws + (size_t)n * SEQ * 32);
    const char* vb = (const char*)(vtws + (size_t)n * CIN * SEQ);

    const char* qp = (const char*)(qws + (size_t)n * SEQ * 32)
                     + (size_t)(qbase + l31) * 64 + h * 16;
    const bf16x8 qf0 = *(const bf16x8*)(qp);
    const bf16x8 qf1 = *(const bf16x8*)(qp + 32);

    f32x16 of0 = {}, of1 = {};
    float ls = 0.f;

    // stage tile (3 gll16 per wave: K 1, V 2) into stg[b]
    auto stage = [&](int k0n, int b) {
        {
            int row = t >> 2;
            int c16 = (t & 3) ^ ((t >> 3) & 3);
            gll16(kb + (size_t)(k0n + row) * 64 + c16 * 16, &stg[b][0] + t * 16);
        }
        #pragma unroll
        for (int j = 0; j < 2; ++j) {
            int L   = j * 4096 + t * 16;
            int row = j * 32 + (t >> 3);
            int c16 = (t & 7) ^ ((t >> 3) & 7);
            gll16(vb + (size_t)row * 8192 + (size_t)k0n * 2 + c16 * 16,
                  &stg[b][4096] + L);
        }
    };

    stage(kbase, 0);
    stage(kbase + KBLK, 1);

    int cur = 0;
    for (int tt = 0; tt < NTC; ++tt) {
        // tile t ready (3 newest = tile t+1's stages may remain in flight)
        if (tt + 1 < NTC) {
            asm volatile("s_waitcnt vmcnt(3)" ::: "memory");
        } else {
            asm volatile("s_waitcnt vmcnt(0)" ::: "memory");
        }
        __builtin_amdgcn_s_barrier();   // raw: no compiler vmcnt(0) drain

        // all waves past barrier => tile (t-1) consumed; safe to overwrite
        if (tt + 2 < NTC) {
            int nb = cur + 2; if (nb >= 3) nb -= 3;
            stage(kbase + (tt + 2) * KBLK, nb);
        }

        const char* kc_ = &stg[cur][0];
        const char* vc_ = &stg[cur][4096];

        unsigned c0[8], c1[8];

        #pragma unroll
        for (int kti = 0; kti < 2; ++kti) {
            const char* krow = kc_ + (size_t)(kti * 32 + l31) * 64;
            bf16x8 kf0 = *(const bf16x8*)(krow + ((h * 16) ^ ksw));
            bf16x8 kf1 = *(const bf16x8*)(krow + ((32 + h * 16) ^ ksw));
            f32x16 s = {};
            __builtin_amdgcn_s_setprio(1);
            s = __builtin_amdgcn_mfma_f32_32x32x16_bf16(kf0, qf0, s, 0, 0, 0);
            s = __builtin_amdgcn_mfma_f32_32x32x16_bf16(kf1, qf1, s, 0, 0, 0);
            __builtin_amdgcn_s_setprio(0);

            float p[16];
            #pragma unroll
            for (int r = 0; r < 16; ++r) {
                p[r] = __builtin_exp2f(s[r]);
                ls += p[r];
            }
            unsigned* c = kti ? c1 : c0;
            #pragma unroll
            for (int j = 0; j < 4; ++j) {
                c[j]     = cvtpk(p[2*j],     p[2*j + 1]);
                c[4 + j] = cvtpk(p[8 + 2*j], p[9 + 2*j]);
            }
            asm("v_permlane32_swap_b32 %0, %1" : "+v"(c[0]), "+v"(c[2]));
            asm("v_permlane32_swap_b32 %0, %1" : "+v"(c[1]), "+v"(c[3]));
            asm("v_permlane32_swap_b32 %0, %1" : "+v"(c[4]), "+v"(c[6]));
            asm("v_permlane32_swap_b32 %0, %1" : "+v"(c[5]), "+v"(c[7]));
        }

        __builtin_amdgcn_s_setprio(1);
        #pragma unroll
        for (int s4 = 0; s4 < 4; ++s4) {
            const unsigned* cs = (s4 < 2) ? c0 : c1;
            const int sl = (s4 & 1) * 4;
            i32x4 bi = { (int)cs[sl], (int)cs[sl+1], (int)cs[sl+2], (int)cs[sl+3] };
            bf16x8 pf = __builtin_bit_cast(bf16x8, bi);
            const int colv = (s4 * 32 + h * 16) ^ vsw;
            bf16x8 vf0 = *(const bf16x8*)(vc_ + (size_t)l31 * 128 + colv);
            bf16x8 vf1 = *(const bf16x8*)(vc_ + (size_t)(32 + l31) * 128 + colv);
            of0 = __builtin_amdgcn_mfma_f32_32x32x16_bf16(vf0, pf, of0, 0, 0, 0);
            of1 = __builtin_amdgcn_mfma_f32_32x32x16_bf16(vf1, pf, of1, 0, 0, 0);
        }
        __builtin_amdgcn_s_setprio(0);

        cur = (cur == 2) ? 0 : cur + 1;
    }

    // ---- epilogue: accumulate partial O and l (f32 atomics) ----
    const int qg = qbase + l31;
    float* Ob = Ows + (size_t)n * CIN * SEQ;
    #pragma unroll
    for (int r = 0; r < 16; ++r) {
        int dv = (r & 3) + 8 * (r >> 2) + 4 * h;
        unsafeAtomicAdd(Ob + (size_t)dv * SEQ + qg,        of0[r]);
        unsafeAtomicAdd(Ob + (size_t)(dv + 32) * SEQ + qg, of1[r]);
    }
    unsafeAtomicAdd(lws + n * SEQ + qg, ls);
}

// ---------------------------------------------------------------------------
// Kernel 3: out = O/l + x  (vectorized f32x4 grid-stride)
// ---------------------------------------------------------------------------
__global__ __launch_bounds__(256) void combine(
    const float* __restrict__ Ows, const float* __restrict__ lws,
    const float* __restrict__ x, float* __restrict__ out)
{
    const int total = 8 * CIN * SEQ / 4;     // 524288 f32x4
    for (int i = blockIdx.x * 256 + threadIdx.x; i < total; i += gridDim.x * 256) {
        int q4 = i & (SEQ / 4 - 1);
        int nd = i >> 10;                    // n*64 + dv
        int n  = nd >> 6;
        f32x4 o4 = *(const f32x4*)(Ows + (size_t)i * 4);
        f32x4 l4 = *(const f32x4*)(lws + (size_t)n * SEQ + q4 * 4);
        f32x4 x4 = *(const f32x4*)(x + (size_t)i * 4);
        f32x4 r;
        r[0] = o4[0] / l4[0] + x4[0];
        r[1] = o4[1] / l4[1] + x4[1];
        r[2] = o4[2] / l4[2] + x4[2];
        r[3] = o4[3] / l4[3] + x4[3];
        *(f32x4*)(out + (size_t)i * 4) = r;
    }
}

extern "C" void kernel_launch(void* const* d_in, const int* in_sizes, int n_in,
                              void* d_out, int out_size, void* d_ws, size_t ws_size,
                              hipStream_t stream)
{
    (void)in_sizes; (void)n_in; (void)out_size; (void)ws_size;
    const float* x  = (const float*)d_in[0];
    const float* w1 = (const float*)d_in[1];
    const float* b1 = (const float*)d_in[2];
    const float* a1 = (const float*)d_in[3];
    const float* w2 = (const float*)d_in[4];
    const float* b2 = (const float*)d_in[5];
    const float* a2 = (const float*)d_in[6];
    const float* w3 = (const float*)d_in[7];
    const float* b3 = (const float*)d_in[8];
    const float* a3 = (const float*)d_in[9];
    float* out = (float*)d_out;

    char* ws = (char*)d_ws;
    __bf16* qws  = (__bf16*)(ws);                        // 2 MB
    __bf16* kws  = (__bf16*)(ws + (2u << 20));           // 2 MB
    __bf16* vtws = (__bf16*)(ws + (4u << 20));           // 4 MB
    float*  Ows  = (float*)(ws + (8u << 20));            // 8 MB  [8][64][4096] f32
    float*  lws  = (float*)(ws + (16u << 20));           // 128 KB [8][4096] f32

    hipMemsetAsync(Ows, 0, (8u << 20) + (128u << 10), stream);
    hipLaunchKernelGGL(qkv_gen, dim3(512), dim3(256), 0, stream,
                       x, w1, b1, a1, w2, b2, a2, w3, b3, a3, qws, kws, vtws);
    hipLaunchKernelGGL(attn, dim3(8 * 32 * KSPLIT), dim3(256), 0, stream,
                       qws, kws, vtws, Ows, lws);
    hipLaunchKernelGGL(combine, dim3(1024), dim3(256), 0, stream,
                       Ows, lws, x, out);
}

// Round 8
// 81.482 us; speedup vs baseline: 1.5895x; 1.1161x over previous
//
#include <hip/hip_runtime.h>
#include <hip/hip_bf16.h>

typedef __bf16 bf16x8 __attribute__((ext_vector_type(8)));
typedef float  f32x4  __attribute__((ext_vector_type(4)));
typedef float  f32x16 __attribute__((ext_vector_type(16)));
typedef int    i32x4  __attribute__((ext_vector_type(4)));

#define SEQ 4096
#define CIN 64
#define KBLK 64
#define KSPLIT 4
#define KCHUNK (SEQ / KSPLIT)          // 1024 keys per block
#define NTC (KCHUNK / KBLK)            // 16 iters
#define LOG2E 1.44269504088896340736f

__device__ __forceinline__ void gll16(const void* g, void* l) {
    __builtin_amdgcn_global_load_lds(
        (const __attribute__((address_space(1))) void*)g,
        (__attribute__((address_space(3))) void*)l, 16, 0, 0);
}

__device__ __forceinline__ unsigned cvtpk(float lo, float hi) {
    unsigned r;
    asm("v_cvt_pk_bf16_f32 %0, %1, %2" : "=v"(r) : "v"(lo), "v"(hi));
    return r;
}

// ---------------------------------------------------------------------------
// Kernel 1: fused conv1x1 + PReLU producing Q,K (as [n][4096][32] bf16) and
// Vt (as [n][64][4096] bf16). Q pre-scaled by log2(e) so attn uses exp2.
// ---------------------------------------------------------------------------
__global__ __launch_bounds__(256, 2) void qkv_gen(
    const float* __restrict__ x,
    const float* __restrict__ w1, const float* __restrict__ b1, const float* __restrict__ a1,
    const float* __restrict__ w2, const float* __restrict__ b2, const float* __restrict__ a2,
    const float* __restrict__ w3, const float* __restrict__ b3, const float* __restrict__ a3,
    __bf16* __restrict__ qws, __bf16* __restrict__ kws, __bf16* __restrict__ vtws)
{
    __shared__ float xs[CIN][64];
    __shared__ float wl[CIN][128];
    __shared__ float bl[128];
    __shared__ float al[4];

    const int t  = threadIdx.x;
    const int n  = blockIdx.x >> 6;
    const int p0 = (blockIdx.x & 63) << 6;

    for (int idx = t; idx < 2048; idx += 256) {
        int j = idx >> 6, c = idx & 63;
        wl[c][j]      = w1[idx];
        wl[c][32 + j] = w2[idx];
    }
    for (int idx = t; idx < 4096; idx += 256) {
        int j = idx >> 6, c = idx & 63;
        wl[c][64 + j] = w3[idx];
    }
    if (t < 32) { bl[t] = b1[t]; bl[32 + t] = b2[t]; }
    if (t >= 128 && t < 192) bl[64 + (t - 128)] = b3[t - 128];
    if (t == 0) { al[0] = a1[0]; al[1] = a2[0]; al[2] = a3[0]; }

    const float* xb = x + ((size_t)n * CIN) * SEQ + p0;
    for (int r = 0; r < 16; ++r) {
        int e = r * 256 + t;
        xs[e >> 6][e & 63] = xb[(size_t)(e >> 6) * SEQ + (e & 63)];
    }
    __syncthreads();

    const int p  = t & 63;
    const int g  = t >> 6;
    const int jb = g << 5;
    const float a = (g == 0) ? al[0] : ((g == 1) ? al[1] : al[2]);

    float acc[32];
    #pragma unroll
    for (int j = 0; j < 32; ++j) acc[j] = bl[jb + j];

    for (int c = 0; c < CIN; ++c) {
        float xv = xs[c][p];
        const f32x4* wr = (const f32x4*)&wl[c][jb];
        #pragma unroll
        for (int j4 = 0; j4 < 8; ++j4) {
            f32x4 wv = wr[j4];
            acc[j4*4+0] = fmaf(wv[0], xv, acc[j4*4+0]);
            acc[j4*4+1] = fmaf(wv[1], xv, acc[j4*4+1]);
            acc[j4*4+2] = fmaf(wv[2], xv, acc[j4*4+2]);
            acc[j4*4+3] = fmaf(wv[3], xv, acc[j4*4+3]);
        }
    }
    #pragma unroll
    for (int j = 0; j < 32; ++j) acc[j] = acc[j] >= 0.f ? acc[j] : a * acc[j];

    const int pg = p0 + p;
    if (g <= 1) {
        const float sc = (g == 0) ? LOG2E : 1.0f;
        __bf16* dst = (g == 0 ? qws : kws) + ((size_t)n * SEQ + pg) * 32;
        #pragma unroll
        for (int v8 = 0; v8 < 4; ++v8) {
            bf16x8 o;
            #pragma unroll
            for (int i = 0; i < 8; ++i) o[i] = (__bf16)(acc[v8*8+i] * sc);
            *(bf16x8*)(dst + v8*8) = o;
        }
    } else {
        __bf16* dst = vtws + ((size_t)n * CIN + (jb - 64)) * SEQ + pg;
        #pragma unroll
        for (int j = 0; j < 32; ++j) dst[(size_t)j * SEQ] = (__bf16)acc[j];
    }
}

// ---------------------------------------------------------------------------
// Kernel 2: flash attention, 32x32 MFMA, in-register P, K-SPLIT partials,
// 3-deep counted-vmcnt pipeline (unchanged from r7).
// ATOMIC=0: each ksplit block writes partial O/l to its OWN buffer slice
// (race-free plain stores; combine4 sums). ATOMIC=1: legacy atomic path
// (fallback when ws_size is too small for the split buffers).
// ---------------------------------------------------------------------------
template<int ATOMIC>
__global__ __launch_bounds__(256, 4) void attn(
    const __bf16* __restrict__ qws, const __bf16* __restrict__ kws,
    const __bf16* __restrict__ vtws,
    float* __restrict__ Ows, float* __restrict__ lws)
{
    __shared__ __align__(16) char stg[3][12288];   // per stage: K @0 (4KB), V @4096 (8KB)

    const int t    = threadIdx.x;     // 256 threads, 4 waves
    const int lane = t & 63;
    const int n    = blockIdx.x & 7;
    const int qblk = (blockIdx.x >> 3) & 31;
    const int ks   = blockIdx.x >> 8;
    const int wid  = t >> 6;
    const int l31  = lane & 31;
    const int h    = lane >> 5;
    const int qbase = qblk * 128 + wid * 32;
    const int kbase = ks * KCHUNK;
    const int ksw  = ((l31 >> 1) & 3) << 4;
    const int vsw  = (l31 & 7) << 4;

    const char* kb = (const char*)(kws + (size_t)n * SEQ * 32);
    const char* vb = (const char*)(vtws + (size_t)n * CIN * SEQ);

    const char* qp = (const char*)(qws + (size_t)n * SEQ * 32)
                     + (size_t)(qbase + l31) * 64 + h * 16;
    const bf16x8 qf0 = *(const bf16x8*)(qp);
    const bf16x8 qf1 = *(const bf16x8*)(qp + 32);

    f32x16 of0 = {}, of1 = {};
    float ls = 0.f;

    auto stage = [&](int k0n, int b) {
        {
            int row = t >> 2;
            int c16 = (t & 3) ^ ((t >> 3) & 3);
            gll16(kb + (size_t)(k0n + row) * 64 + c16 * 16, &stg[b][0] + t * 16);
        }
        #pragma unroll
        for (int j = 0; j < 2; ++j) {
            int L   = j * 4096 + t * 16;
            int row = j * 32 + (t >> 3);
            int c16 = (t & 7) ^ ((t >> 3) & 7);
            gll16(vb + (size_t)row * 8192 + (size_t)k0n * 2 + c16 * 16,
                  &stg[b][4096] + L);
        }
    };

    stage(kbase, 0);
    stage(kbase + KBLK, 1);

    int cur = 0;
    for (int tt = 0; tt < NTC; ++tt) {
        if (tt + 1 < NTC) {
            asm volatile("s_waitcnt vmcnt(3)" ::: "memory");
        } else {
            asm volatile("s_waitcnt vmcnt(0)" ::: "memory");
        }
        __builtin_amdgcn_s_barrier();

        if (tt + 2 < NTC) {
            int nb = cur + 2; if (nb >= 3) nb -= 3;
            stage(kbase + (tt + 2) * KBLK, nb);
        }

        const char* kc_ = &stg[cur][0];
        const char* vc_ = &stg[cur][4096];

        unsigned c0[8], c1[8];

        #pragma unroll
        for (int kti = 0; kti < 2; ++kti) {
            const char* krow = kc_ + (size_t)(kti * 32 + l31) * 64;
            bf16x8 kf0 = *(const bf16x8*)(krow + ((h * 16) ^ ksw));
            bf16x8 kf1 = *(const bf16x8*)(krow + ((32 + h * 16) ^ ksw));
            f32x16 s = {};
            __builtin_amdgcn_s_setprio(1);
            s = __builtin_amdgcn_mfma_f32_32x32x16_bf16(kf0, qf0, s, 0, 0, 0);
            s = __builtin_amdgcn_mfma_f32_32x32x16_bf16(kf1, qf1, s, 0, 0, 0);
            __builtin_amdgcn_s_setprio(0);

            float p[16];
            #pragma unroll
            for (int r = 0; r < 16; ++r) {
                p[r] = __builtin_exp2f(s[r]);
                ls += p[r];
            }
            unsigned* c = kti ? c1 : c0;
            #pragma unroll
            for (int j = 0; j < 4; ++j) {
                c[j]     = cvtpk(p[2*j],     p[2*j + 1]);
                c[4 + j] = cvtpk(p[8 + 2*j], p[9 + 2*j]);
            }
            asm("v_permlane32_swap_b32 %0, %1" : "+v"(c[0]), "+v"(c[2]));
            asm("v_permlane32_swap_b32 %0, %1" : "+v"(c[1]), "+v"(c[3]));
            asm("v_permlane32_swap_b32 %0, %1" : "+v"(c[4]), "+v"(c[6]));
            asm("v_permlane32_swap_b32 %0, %1" : "+v"(c[5]), "+v"(c[7]));
        }

        __builtin_amdgcn_s_setprio(1);
        #pragma unroll
        for (int s4 = 0; s4 < 4; ++s4) {
            const unsigned* cs = (s4 < 2) ? c0 : c1;
            const int sl = (s4 & 1) * 4;
            i32x4 bi = { (int)cs[sl], (int)cs[sl+1], (int)cs[sl+2], (int)cs[sl+3] };
            bf16x8 pf = __builtin_bit_cast(bf16x8, bi);
            const int colv = (s4 * 32 + h * 16) ^ vsw;
            bf16x8 vf0 = *(const bf16x8*)(vc_ + (size_t)l31 * 128 + colv);
            bf16x8 vf1 = *(const bf16x8*)(vc_ + (size_t)(32 + l31) * 128 + colv);
            of0 = __builtin_amdgcn_mfma_f32_32x32x16_bf16(vf0, pf, of0, 0, 0, 0);
            of1 = __builtin_amdgcn_mfma_f32_32x32x16_bf16(vf1, pf, of1, 0, 0, 0);
        }
        __builtin_amdgcn_s_setprio(0);

        cur = (cur == 2) ? 0 : cur + 1;
    }

    // ---- epilogue: partial O and l ----
    const int qg = qbase + l31;
    if (ATOMIC) {
        float* Ob = Ows + (size_t)n * CIN * SEQ;
        #pragma unroll
        for (int r = 0; r < 16; ++r) {
            int dv = (r & 3) + 8 * (r >> 2) + 4 * h;
            unsafeAtomicAdd(Ob + (size_t)dv * SEQ + qg,        of0[r]);
            unsafeAtomicAdd(Ob + (size_t)(dv + 32) * SEQ + qg, of1[r]);
        }
        unsafeAtomicAdd(lws + n * SEQ + qg, ls);
    } else {
        // race-free plain stores: each (lane,r) owns a unique (dv,qg) slot
        float* Ob = Ows + (size_t)ks * (8 * CIN * SEQ) + (size_t)n * CIN * SEQ;
        #pragma unroll
        for (int r = 0; r < 16; ++r) {
            int dv = (r & 3) + 8 * (r >> 2) + 4 * h;
            Ob[(size_t)dv * SEQ + qg]        = of0[r];
            Ob[(size_t)(dv + 32) * SEQ + qg] = of1[r];
        }
        float lt = ls + __shfl_xor(ls, 32);
        if (h == 0) lws[(size_t)ks * (8 * SEQ) + n * SEQ + qg] = lt;
    }
}

// ---------------------------------------------------------------------------
// Kernel 3a: combine4 — out = (sum_ks O_ks) / (sum_ks l_ks) + x
// ---------------------------------------------------------------------------
__global__ __launch_bounds__(256) void combine4(
    const float* __restrict__ O4, const float* __restrict__ l4,
    const float* __restrict__ x, float* __restrict__ out)
{
    const int total = 8 * CIN * SEQ / 4;        // 524288 x4-units
    const f32x4* Op = (const f32x4*)O4;
    const f32x4* lp = (const f32x4*)l4;
    for (int i = blockIdx.x * 256 + threadIdx.x; i < total; i += gridDim.x * 256) {
        int n  = i >> 16;                       // 65536 x4 per n
        int q4 = i & 1023;
        f32x4 o = Op[i];
        o += Op[i + 524288];
        o += Op[i + 2 * 524288];
        o += Op[i + 3 * 524288];
        int lb = n * 1024 + q4;
        f32x4 l = lp[lb];
        l += lp[lb + 8192];
        l += lp[lb + 2 * 8192];
        l += lp[lb + 3 * 8192];
        f32x4 x4 = *(const f32x4*)(x + (size_t)i * 4);
        f32x4 r;
        r[0] = o[0] / l[0] + x4[0];
        r[1] = o[1] / l[1] + x4[1];
        r[2] = o[2] / l[2] + x4[2];
        r[3] = o[3] / l[3] + x4[3];
        *(f32x4*)(out + (size_t)i * 4) = r;
    }
}

// ---------------------------------------------------------------------------
// Kernel 3b: combine1 — legacy (atomic-accumulated single buffer)
// ---------------------------------------------------------------------------
__global__ __launch_bounds__(256) void combine1(
    const float* __restrict__ Ows, const float* __restrict__ lws,
    const float* __restrict__ x, float* __restrict__ out)
{
    const int total = 8 * CIN * SEQ / 4;
    for (int i = blockIdx.x * 256 + threadIdx.x; i < total; i += gridDim.x * 256) {
        int q4 = i & 1023;
        int n  = i >> 16;
        f32x4 o4 = *(const f32x4*)(Ows + (size_t)i * 4);
        f32x4 l4 = *(const f32x4*)(lws + (size_t)n * SEQ + q4 * 4);
        f32x4 x4 = *(const f32x4*)(x + (size_t)i * 4);
        f32x4 r;
        r[0] = o4[0] / l4[0] + x4[0];
        r[1] = o4[1] / l4[1] + x4[1];
        r[2] = o4[2] / l4[2] + x4[2];
        r[3] = o4[3] / l4[3] + x4[3];
        *(f32x4*)(out + (size_t)i * 4) = r;
    }
}

extern "C" void kernel_launch(void* const* d_in, const int* in_sizes, int n_in,
                              void* d_out, int out_size, void* d_ws, size_t ws_size,
                              hipStream_t stream)
{
    (void)in_sizes; (void)n_in; (void)out_size;
    const float* x  = (const float*)d_in[0];
    const float* w1 = (const float*)d_in[1];
    const float* b1 = (const float*)d_in[2];
    const float* a1 = (const float*)d_in[3];
    const float* w2 = (const float*)d_in[4];
    const float* b2 = (const float*)d_in[5];
    const float* a2 = (const float*)d_in[6];
    const float* w3 = (const float*)d_in[7];
    const float* b3 = (const float*)d_in[8];
    const float* a3 = (const float*)d_in[9];
    float* out = (float*)d_out;

    char* ws = (char*)d_ws;
    __bf16* qws  = (__bf16*)(ws);                        // 2 MB
    __bf16* kws  = (__bf16*)(ws + (2u << 20));           // 2 MB
    __bf16* vtws = (__bf16*)(ws + (4u << 20));           // 4 MB

    hipLaunchKernelGGL(qkv_gen, dim3(512), dim3(256), 0, stream,
                       x, w1, b1, a1, w2, b2, a2, w3, b3, a3, qws, kws, vtws);

    const size_t need_split = (8u << 20) + (32u << 20) + (512u << 10);
    if (ws_size >= need_split) {
        // split partial buffers, no atomics, no memset
        float* Ows4 = (float*)(ws + (8u << 20));          // 32 MB [4][8][64][4096]
        float* lws4 = (float*)(ws + (40u << 20));         // 512 KB [4][8][4096]
        hipLaunchKernelGGL(attn<0>, dim3(8 * 32 * KSPLIT), dim3(256), 0, stream,
                           qws, kws, vtws, Ows4, lws4);
        hipLaunchKernelGGL(combine4, dim3(1024), dim3(256), 0, stream,
                           Ows4, lws4, x, out);
    } else {
        // legacy atomic fallback
        float* Ows = (float*)(ws + (8u << 20));           // 8 MB
        float* lws = (float*)(ws + (16u << 20));          // 128 KB
        hipMemsetAsync(Ows, 0, (8u << 20) + (128u << 10), stream);
        hipLaunchKernelGGL(attn<1>, dim3(8 * 32 * KSPLIT), dim3(256), 0, stream,
                           qws, kws, vtws, Ows, lws);
        hipLaunchKernelGGL(combine1, dim3(1024), dim3(256), 0, stream,
                           Ows, lws, x, out);
    }
}